// Round 3
// baseline (758.695 us; speedup 1.0000x reference)
//
#include <hip/hip_runtime.h>
#include <hip/hip_cooperative_groups.h>
#include <math.h>

namespace cg = cooperative_groups;

// Problem: IN=8192, HID=8192, OUT=1024, fp32.
// out = spiking_layer(spiking_layer(exp(x), W1), W2)
// Monotone-predicate reduction: per-row scan -> binary search over sorted z;
// Wc = prefix/suffix sum of W row in sorted-z order (suffix side when k>n/2,
// which for this data is 1 gathered element per row).
//
// Structure: 1 tiny prezero kernel + 1 cooperative uber kernel.
// Uber kernel: blocks [0,NS) run the layer-1 sort chain (exp -> rank ->
// scatter -> scan) behind private atomic sub-barriers WHILE blocks [NS,NB)
// stream the mandatory 288 MiB row-sum of W1+W2 (the only BW-bound part,
// ~47 us). Then 5 grid.sync()s: finalize1 -> rank2 -> scatter2 -> scan2 ->
// finalize2.

static constexpr int NN   = 8192;   // columns of both W's; layer-1/2 input dim
static constexpr int HID  = 8192;
static constexpr int OUTN = 1024;
static constexpr int NB   = 512;    // grid blocks (2/CU co-resident)
static constexpr int BT   = 256;    // threads/block
static constexpr int NS   = 128;    // sort-crew blocks
static constexpr int NR   = NB - NS;
static constexpr int TOTROWS = HID + OUTN;  // 9216

// Map float to uint with total order matching float <  (handles negatives/inf).
__device__ inline unsigned f2ord(float f) {
    unsigned u = __float_as_uint(f);
    return (u & 0x80000000u) ? ~u : (u | 0x80000000u);
}
__device__ inline unsigned long long sortkey(float f, int j) {
    return (((unsigned long long)f2ord(f)) << 13) | (unsigned)j;   // j < 8192
}

// Sub-barrier among the first `target` blocks (co-resident via cooperative
// launch, so spinning is deadlock-free). Device-scope atomics + fences (G16).
__device__ inline void crew_barrier(unsigned* ctr, unsigned target) {
    __syncthreads();
    if (threadIdx.x == 0) {
        __threadfence();                       // release
        atomicAdd(ctr, 1u);
        while (atomicAdd(ctr, 0u) < target) {} // device-scope RMW read
        __threadfence();                       // acquire
    }
    __syncthreads();
}

// Exclusive scan of 8192 floats by ONE block of 256 threads. cs[0..8192].
__device__ inline void scan8192_block(const float* __restrict__ src,
                                      float* __restrict__ cs) {
    __shared__ float wsum_s[4];
    __shared__ float woff_s[4];
    int t = threadIdx.x, lane = t & 63, wv = t >> 6;
    float v[32];
    const float4* p = (const float4*)(src + t * 32);
#pragma unroll
    for (int i = 0; i < 8; ++i) {
        float4 q = p[i];
        v[4*i] = q.x; v[4*i+1] = q.y; v[4*i+2] = q.z; v[4*i+3] = q.w;
    }
    float s = 0.f;
#pragma unroll
    for (int i = 0; i < 32; ++i) s += v[i];
    float sc = s;                               // inclusive wave scan
    for (int off = 1; off < 64; off <<= 1) {
        float up = __shfl_up(sc, off);
        if (lane >= off) sc += up;
    }
    if (lane == 63) wsum_s[wv] = sc;
    __syncthreads();
    if (t == 0) {
        float acc = 0.f;
        for (int w = 0; w < 4; ++w) { woff_s[w] = acc; acc += wsum_s[w]; }
    }
    __syncthreads();
    float run = woff_s[wv] + (sc - s);          // exclusive base for this thread
    float* dst = cs + t * 32;
#pragma unroll
    for (int i = 0; i < 32; ++i) { dst[i] = run; run += v[i]; }
    if (t == 255) cs[NN] = run;                 // Zsum
}

// One wave handles one output row: k via monotone-predicate binary search
// (all 64 lanes run it uniformly), then gather over the cheaper side.
__device__ inline void finalize_row_wave(const float* __restrict__ Wrow, float Wsum,
                                         const float* __restrict__ zs,
                                         const int* __restrict__ idx,
                                         const float* __restrict__ csZ,
                                         float* __restrict__ outp) {
    int lane = threadIdx.x & 63;
    float Zsum = csZ[NN];
    float tmp = Wsum * Zsum / (Wsum - 1.0f);
    bool fc = Wsum > 1.0f;
    int k = 0; bool empty = false;
    if (fc) {
        if (zs[0] <= tmp) k = NN - 1; else empty = true;
    } else {
        if (tmp < zs[NN - 1]) {
            int lo = 0, hi = NN;                 // c = #{i : zs[i] <= tmp}
            while (lo < hi) { int mid = (lo + hi) >> 1; if (zs[mid] <= tmp) lo = mid + 1; else hi = mid; }
            int c = lo;
            if (c == 0) k = NN - 1;
            else if (c == 1) empty = true;       // k==0 -> empty
            else k = c - 1;
        } else empty = true;
    }
    if (empty) { if (lane == 0) *outp = __builtin_inff(); return; }
    float part = 0.f;
    bool fwd = (2 * k <= NN);
    if (fwd) { for (int t2 = lane;     t2 < k;  t2 += 64) part += Wrow[idx[t2]]; }
    else     { for (int t2 = k + lane; t2 < NN; t2 += 64) part += Wrow[idx[t2]]; }
    for (int off = 32; off > 0; off >>= 1) part += __shfl_down(part, off);
    if (lane == 0) {
        float Wc = fwd ? part : (Wsum - part);
        *outp = Wc * csZ[k] / (Wc - 1.0f);
    }
}

__global__ void prezero_kernel(int* __restrict__ rank12, unsigned* __restrict__ ctrs) {
    int i = blockIdx.x * blockDim.x + threadIdx.x;
    if (i < 2 * NN) rank12[i] = 0;
    if (i < 16) ctrs[i] = 0;
}

__global__ void __launch_bounds__(BT, 2) uber_kernel(
    const float* __restrict__ x, const float* __restrict__ W1,
    const float* __restrict__ W2, float* __restrict__ out,
    float* __restrict__ z1, float* __restrict__ zs1, float* __restrict__ csZ1,
    float* __restrict__ Wsum1, float* __restrict__ z2, float* __restrict__ zs2,
    float* __restrict__ csZ2, float* __restrict__ Wsum2,
    int* __restrict__ idx1, int* __restrict__ idx2,
    int* __restrict__ rank1, int* __restrict__ rank2, unsigned* __restrict__ ctrs)
{
    cg::grid_group grid = cg::this_grid();
    const int b = blockIdx.x, t = threadIdx.x;
    __shared__ unsigned long long zt64[1024];   // rank key staging (8 KB)
    __shared__ float red4[4];

    if (b < NS) {
        // ---------------- sort crew: layer-1 chain ----------------
        // S0: z1 = exp(x)
        for (int i = b * BT + t; i < NN; i += NS * BT) z1[i] = expf(x[i]);
        crew_barrier(&ctrs[0], NS);
        // S1: rank1 — 32 j-tiles x 4 column-quarters; 64-bit stable keys.
        {
            int jt = b >> 2, q = b & 3;
            int j = jt * BT + t;
            unsigned long long K = sortkey(z1[j], j);
            int cnt = 0;
            for (int c = 0; c < 2; ++c) {            // 2 stages of 1024
                int base = q * 2048 + c * 1024;
                __syncthreads();
                for (int i = t; i < 1024; i += BT) zt64[i] = sortkey(z1[base + i], base + i);
                __syncthreads();
#pragma unroll 4
                for (int i = 0; i < 1024; ++i) cnt += (zt64[i] < K) ? 1 : 0;
            }
            atomicAdd(&rank1[j], cnt);
        }
        crew_barrier(&ctrs[1], NS);
        // S2: scatter1 (atomic read of rank for cross-XCD coherence)
        for (int j = b * BT + t; j < NN; j += NS * BT) {
            int r = atomicAdd(&rank1[j], 0);
            zs1[r] = z1[j];
            idx1[r] = j;
        }
        crew_barrier(&ctrs[2], NS);
        // S3: scan1
        if (b == 0) scan8192_block(zs1, csZ1);
    } else {
        // ---------------- rowsum crew: the one mandatory 288 MiB read ------
        for (int r = b - NS; r < TOTROWS; r += NR) {
            const float* Wr; float* op;
            if (r < HID) { Wr = W1 + (size_t)r * NN;        op = &Wsum1[r]; }
            else         { Wr = W2 + (size_t)(r - HID) * NN; op = &Wsum2[r - HID]; }
            const float4* p4 = (const float4*)Wr;
            float s = 0.f;
            for (int i = t; i < NN / 4; i += BT) {
                float4 q = p4[i];
                s += (q.x + q.y) + (q.z + q.w);
            }
            for (int off = 32; off > 0; off >>= 1) s += __shfl_down(s, off);
            int lane = t & 63, wv = t >> 6;
            __syncthreads();
            if (lane == 0) red4[wv] = s;
            __syncthreads();
            if (t == 0) *op = (red4[0] + red4[1]) + (red4[2] + red4[3]);
        }
    }
    grid.sync();
    // P4: finalize1 -> z2 (wave-per-row: 2048 waves, 4 rows each)
    {
        int wgid = b * (BT / 64) + (t >> 6);
        for (int r = wgid; r < HID; r += NB * (BT / 64))
            finalize_row_wave(W1 + (size_t)r * NN, Wsum1[r], zs1, idx1, csZ1, &z2[r]);
    }
    grid.sync();
    // P5: rank2 — full grid, 32 j-tiles x 16 column-segments of 512.
    {
        int jt = b >> 4, seg = b & 15;
        int j = jt * BT + t;
        unsigned long long K = sortkey(z2[j], j);
        int base = seg * 512;
        __syncthreads();
        for (int i = t; i < 512; i += BT) zt64[i] = sortkey(z2[base + i], base + i);
        __syncthreads();
        int cnt = 0;
#pragma unroll 4
        for (int i = 0; i < 512; ++i) cnt += (zt64[i] < K) ? 1 : 0;
        atomicAdd(&rank2[j], cnt);
    }
    grid.sync();
    // P6: scatter2
    {
        int gid = b * BT + t;
        if (gid < NN) {
            int r = atomicAdd(&rank2[gid], 0);
            zs2[r] = z2[gid];
            idx2[r] = gid;
        }
    }
    grid.sync();
    // P7: scan2
    if (b == 0) scan8192_block(zs2, csZ2);
    grid.sync();
    // P8: finalize2 -> out (first 1024 waves)
    {
        int wgid = b * (BT / 64) + (t >> 6);
        if (wgid < OUTN)
            finalize_row_wave(W2 + (size_t)wgid * NN, Wsum2[wgid], zs2, idx2, csZ2, &out[wgid]);
    }
}

extern "C" void kernel_launch(void* const* d_in, const int* in_sizes, int n_in,
                              void* d_out, int out_size, void* d_ws, size_t ws_size,
                              hipStream_t stream) {
    const float* x  = (const float*)d_in[0];
    const float* W1 = (const float*)d_in[1];   // [8192, 8192]
    const float* W2 = (const float*)d_in[2];   // [1024, 8192]
    float* out = (float*)d_out;                // [1024]

    char* ws = (char*)d_ws;
    size_t off = 0;
    auto alloc = [&](size_t bytes) -> void* {
        void* p = ws + off;
        off += (bytes + 255) & ~(size_t)255;
        return p;
    };
    float* z1    = (float*)alloc((size_t)NN * 4);
    float* zs1   = (float*)alloc((size_t)NN * 4);
    float* csZ1  = (float*)alloc((size_t)(NN + 1) * 4);
    float* Wsum1 = (float*)alloc((size_t)NN * 4);
    float* z2    = (float*)alloc((size_t)NN * 4);
    float* zs2   = (float*)alloc((size_t)NN * 4);
    float* csZ2  = (float*)alloc((size_t)(NN + 1) * 4);
    float* Wsum2 = (float*)alloc((size_t)OUTN * 4);
    int* idx1    = (int*)alloc((size_t)NN * 4);
    int* idx2    = (int*)alloc((size_t)NN * 4);
    int* rank12  = (int*)alloc((size_t)2 * NN * 4);
    unsigned* ctrs = (unsigned*)alloc(16 * 4);
    int* rank1 = rank12;
    int* rank2 = rank12 + NN;

    prezero_kernel<<<(2 * NN + BT - 1) / BT, BT, 0, stream>>>(rank12, ctrs);

    void* kargs[] = {
        (void*)&x, (void*)&W1, (void*)&W2, (void*)&out,
        (void*)&z1, (void*)&zs1, (void*)&csZ1, (void*)&Wsum1,
        (void*)&z2, (void*)&zs2, (void*)&csZ2, (void*)&Wsum2,
        (void*)&idx1, (void*)&idx2, (void*)&rank1, (void*)&rank2, (void*)&ctrs
    };
    hipLaunchCooperativeKernel((const void*)uber_kernel, dim3(NB), dim3(BT),
                               kargs, 0, stream);
}

// Round 4
// 430.121 us; speedup vs baseline: 1.7639x; 1.7639x over previous
//
#include <hip/hip_runtime.h>
#include <math.h>

// Problem: IN=8192, HID=8192, OUT=1024, fp32.
// out = spiking_layer(spiking_layer(exp(x), W1), W2)
// Monotone-predicate reduction: the per-row scan collapses to a binary search
// over sorted z; Wc is a prefix/suffix sum of the W row in sorted-z order.
//
// R3 lesson: cooperative grid.sync / spin barriers cost ~400us on 8 XCDs.
// Kernel boundaries are the cheap device-wide sync. Structure (6 kernels):
//  K1 rank_rowsum : blocks [0,256) partial stable-ranks of z1=exp(x) (VALU,
//                   ~4us) fused with blocks [256,9472) streaming the one
//                   mandatory 288 MiB row-sum of W1+W2 (~46us, hides rank).
//                   Plain partial-count stores -> no memset, no atomics.
//  K2 scatter_scan: 1 block: sum partials -> rank, scatter z/idx, wave scan.
//  K3 finalize1   : k via binary search + adaptive gather -> z2
//  K4 rank2       : 256 blocks, partial ranks of z2
//  K5 scatter_scan2
//  K6 finalize2   -> out

static constexpr int NN     = 8192;   // columns of both W's
static constexpr int HID    = 8192;
static constexpr int OUTN   = 1024;
static constexpr int SEGS   = 8;
static constexpr int SEGLEN = NN / SEGS;     // 1024
static constexpr int RANKB  = 32 * SEGS;     // 256 rank blocks (32 j-tiles x 8 segs)
static constexpr int TOTROWS = HID + OUTN;   // 9216

// Total order on floats matching < (negatives, inf handled).
__device__ inline unsigned f2ord(float f) {
    unsigned u = __float_as_uint(f);
    return (u & 0x80000000u) ? ~u : (u | 0x80000000u);
}
__device__ inline unsigned long long sortkey(float f, int j) {
    return (((unsigned long long)f2ord(f)) << 13) | (unsigned)j;   // j < 8192
}

// Partial stable rank: block (jt,seg) counts, for each j in jt's 256-wide
// tile, how many keys in segment seg are < key(j). Plain store (no zeroing).
template <bool DOEXP>
__device__ inline void rank_block(const float* __restrict__ src,
                                  int* __restrict__ rank_part,
                                  unsigned long long* keys, int b) {
    int t = threadIdx.x;
    int jt = b >> 3, seg = b & 7;
    int j = jt * 256 + t;
    float zj = src[j];
    if (DOEXP) zj = expf(zj);
    unsigned long long K = sortkey(zj, j);
    int base = seg * SEGLEN;
    for (int i = t; i < SEGLEN; i += 256) {
        float zv = src[base + i];
        if (DOEXP) zv = expf(zv);
        keys[i] = sortkey(zv, base + i);
    }
    __syncthreads();
    int cnt = 0;
#pragma unroll 8
    for (int i = 0; i < SEGLEN; ++i) cnt += (keys[i] < K) ? 1 : 0;   // LDS broadcast
    rank_part[seg * NN + j] = cnt;
}

// K1: fused partial-rank (blocks [0,RANKB)) + row sums (blocks [RANKB, ...)).
__global__ void rank_rowsum_kernel(const float* __restrict__ x,
                                   const float* __restrict__ W1,
                                   const float* __restrict__ W2,
                                   int* __restrict__ rank_part,
                                   float* __restrict__ Wsum1,
                                   float* __restrict__ Wsum2) {
    __shared__ unsigned long long keys[SEGLEN];   // 8 KB (rank role)
    __shared__ float red4[4];                     // (rowsum role)
    int b = blockIdx.x, t = threadIdx.x;
    if (b < RANKB) {
        rank_block<true>(x, rank_part, keys, b);
        return;
    }
    int r = b - RANKB;
    const float* Wr; float* op;
    if (r < HID) { Wr = W1 + (size_t)r * NN;         op = &Wsum1[r]; }
    else         { Wr = W2 + (size_t)(r - HID) * NN; op = &Wsum2[r - HID]; }
    const float4* p4 = (const float4*)Wr;
    float s = 0.f;
    for (int i = t; i < NN / 4; i += 256) {
        float4 q = p4[i];
        s += (q.x + q.y) + (q.z + q.w);
    }
    for (int off = 32; off > 0; off >>= 1) s += __shfl_down(s, off);
    int lane = t & 63, wv = t >> 6;
    if (lane == 0) red4[wv] = s;
    __syncthreads();
    if (t == 0) *op = (red4[0] + red4[1]) + (red4[2] + red4[3]);
}

// K4: standalone partial rank of z2 (no exp).
__global__ void rank2_kernel(const float* __restrict__ z2, int* __restrict__ rank_part) {
    __shared__ unsigned long long keys[SEGLEN];
    rank_block<false>(z2, rank_part, keys, blockIdx.x);
}

// K2/K5: single block, 1024 threads. Sum the 8 partial ranks per j, scatter
// z (optionally exp'd) + idx by rank, then exclusive scan -> zs, csZ[0..NN].
template <bool DOEXP>
__global__ void scatter_scan_kernel(const float* __restrict__ src,
                                    const int* __restrict__ rank_part,
                                    float* __restrict__ zs, int* __restrict__ idx,
                                    float* __restrict__ csZ) {
    __shared__ float zs_l[NN];                    // 32 KB
    __shared__ float wsum_s[16], woff_s[16];
    int t = threadIdx.x;
#pragma unroll
    for (int i = 0; i < 8; ++i) {
        int j = t + i * 1024;                     // coalesced
        int r = 0;
#pragma unroll
        for (int s = 0; s < SEGS; ++s) r += rank_part[s * NN + j];
        float z = src[j];
        if (DOEXP) z = expf(z);
        zs_l[r] = z;                              // r is a permutation of [0,NN)
        idx[r] = j;
    }
    __syncthreads();
    int lane = t & 63, wv = t >> 6;               // 16 waves
    int base = t * 8;
    float v[8], s = 0.f;
#pragma unroll
    for (int i = 0; i < 8; ++i) { v[i] = zs_l[base + i]; s += v[i]; }
    float sc = s;                                 // inclusive wave scan of thread sums
    for (int off = 1; off < 64; off <<= 1) {
        float up = __shfl_up(sc, off);
        if (lane >= off) sc += up;
    }
    if (lane == 63) wsum_s[wv] = sc;
    __syncthreads();
    if (t == 0) {
        float acc = 0.f;
        for (int w = 0; w < 16; ++w) { woff_s[w] = acc; acc += wsum_s[w]; }
    }
    __syncthreads();
    float run = woff_s[wv] + (sc - s);            // exclusive base for this thread
#pragma unroll
    for (int i = 0; i < 8; ++i) { zs[base + i] = v[i]; csZ[base + i] = run; run += v[i]; }
    if (t == 1023) csZ[NN] = run;                 // Zsum
}

// K3/K6: one block per output row (byte-identical logic to the R2 version
// that measured absmax 0.0): k via monotone-predicate binary search, then
// Wc via gather over the cheaper of {first k, last n-k} sorted columns.
__global__ void finalize_kernel(const float* __restrict__ W,
                                const float* __restrict__ Wsum_arr,
                                const float* __restrict__ zs,
                                const int* __restrict__ idx,
                                const float* __restrict__ csZ, int n,
                                float* __restrict__ out) {
    int o = blockIdx.x;
    __shared__ int sk;
    __shared__ int smode;   // 0 = empty (inf), 1 = forward gather, 2 = backward gather
    __shared__ float sred[4];
    if (threadIdx.x == 0) {
        float Wsum = Wsum_arr[o];
        float Zsum = csZ[n];
        float tmp = Wsum * Zsum / (Wsum - 1.0f);
        bool fc = Wsum > 1.0f;
        int k = 0;
        bool empty = false;
        if (fc) {
            if (zs[0] <= tmp) k = n - 1; else empty = true;
        } else {
            if (tmp < zs[n - 1]) {
                int lo = 0, hi = n;               // c = #{i : zs[i] <= tmp}
                while (lo < hi) {
                    int mid = (lo + hi) >> 1;
                    if (zs[mid] <= tmp) lo = mid + 1; else hi = mid;
                }
                int c = lo;
                if (c == 0) k = n - 1;
                else if (c == 1) empty = true;    // k==0 -> empty
                else k = c - 1;
            } else empty = true;
        }
        sk = k;
        smode = empty ? 0 : ((2 * k <= n) ? 1 : 2);
    }
    __syncthreads();
    int mode = smode;
    if (mode == 0) {
        if (threadIdx.x == 0) out[o] = __builtin_inff();
        return;
    }
    int k = sk;
    const float* Wrow = W + (size_t)o * n;
    float part = 0.f;
    if (mode == 1) {
        for (int t = threadIdx.x; t < k; t += blockDim.x) part += Wrow[idx[t]];
    } else {
        for (int t = k + threadIdx.x; t < n; t += blockDim.x) part += Wrow[idx[t]];
    }
    for (int off = 32; off > 0; off >>= 1) part += __shfl_down(part, off);
    int lane = threadIdx.x & 63, wv = threadIdx.x >> 6;
    if (lane == 0) sred[wv] = part;
    __syncthreads();
    if (threadIdx.x == 0) {
        float S = 0.f;
        int nw = blockDim.x >> 6;
        for (int w = 0; w < nw; ++w) S += sred[w];
        float Wsum = Wsum_arr[o];
        float Wc = (mode == 1) ? S : (Wsum - S);
        float Zc = csZ[k];
        out[o] = Wc * Zc / (Wc - 1.0f);
    }
}

extern "C" void kernel_launch(void* const* d_in, const int* in_sizes, int n_in,
                              void* d_out, int out_size, void* d_ws, size_t ws_size,
                              hipStream_t stream) {
    const float* x  = (const float*)d_in[0];
    const float* W1 = (const float*)d_in[1];   // [8192, 8192]
    const float* W2 = (const float*)d_in[2];   // [1024, 8192]
    float* out = (float*)d_out;                // [1024]

    char* ws = (char*)d_ws;
    size_t off = 0;
    auto alloc = [&](size_t bytes) -> void* {
        void* p = ws + off;
        off += (bytes + 255) & ~(size_t)255;
        return p;
    };
    float* zs1   = (float*)alloc((size_t)NN * 4);
    float* csZ1  = (float*)alloc((size_t)(NN + 1) * 4);
    float* Wsum1 = (float*)alloc((size_t)NN * 4);
    float* z2    = (float*)alloc((size_t)NN * 4);
    float* zs2   = (float*)alloc((size_t)NN * 4);
    float* csZ2  = (float*)alloc((size_t)(NN + 1) * 4);
    float* Wsum2 = (float*)alloc((size_t)OUTN * 4);
    int* idx1    = (int*)alloc((size_t)NN * 4);
    int* idx2    = (int*)alloc((size_t)NN * 4);
    int* rank1_part = (int*)alloc((size_t)SEGS * NN * 4);   // plain stores, no zeroing
    int* rank2_part = (int*)alloc((size_t)SEGS * NN * 4);

    // K1: fused partial-rank(z1) + row sums of W1|W2 (the mandatory 288 MiB read)
    rank_rowsum_kernel<<<RANKB + TOTROWS, 256, 0, stream>>>(x, W1, W2,
                                                            rank1_part, Wsum1, Wsum2);
    // K2: gather partials -> scatter -> scan
    scatter_scan_kernel<true><<<1, 1024, 0, stream>>>(x, rank1_part, zs1, idx1, csZ1);
    // K3: finalize layer 1 -> z2
    finalize_kernel<<<HID, 256, 0, stream>>>(W1, Wsum1, zs1, idx1, csZ1, NN, z2);
    // K4: partial ranks of z2
    rank2_kernel<<<RANKB, 256, 0, stream>>>(z2, rank2_part);
    // K5
    scatter_scan_kernel<false><<<1, 1024, 0, stream>>>(z2, rank2_part, zs2, idx2, csZ2);
    // K6: finalize layer 2 -> out
    finalize_kernel<<<OUTN, 256, 0, stream>>>(W2, Wsum2, zs2, idx2, csZ2, NN, out);
}